// Round 1
// baseline (754.923 us; speedup 1.0000x reference)
//
#include <hip/hip_runtime.h>

#define D 128
#define NEDGES 500000
#define NNODES 100000

typedef short short8 __attribute__((ext_vector_type(8)));
typedef float f32x4 __attribute__((ext_vector_type(4)));
typedef unsigned short us4 __attribute__((ext_vector_type(4)));

static __device__ __forceinline__ unsigned short f2bf(float f) {
  unsigned u = __builtin_bit_cast(unsigned, f);
  u += 0x7fff + ((u >> 16) & 1);   // RNE
  return (unsigned short)(u >> 16);
}

static __device__ __forceinline__ short8 cvt8(const float* p) {
  f32x4 a = *(const f32x4*)p;
  f32x4 b = *(const f32x4*)(p + 4);
  short8 r;
  r[0] = (short)f2bf(a[0]); r[1] = (short)f2bf(a[1]);
  r[2] = (short)f2bf(a[2]); r[3] = (short)f2bf(a[3]);
  r[4] = (short)f2bf(b[0]); r[5] = (short)f2bf(b[1]);
  r[6] = (short)f2bf(b[2]); r[7] = (short)f2bf(b[3]);
  return r;
}

// Transpose + bf16-convert weights into workspace.
// Wt1[h][k] = W1[k][h]  (h<128 hidden, k<384 input)   -> 128*384 us
// Wt2[o][h] = W2[h][o]  (o<128 out,    h<128 hidden)  -> 128*128 us
__global__ void prep_weights(const float* __restrict__ W1,
                             const float* __restrict__ W2,
                             unsigned short* __restrict__ Wt1,
                             unsigned short* __restrict__ Wt2) {
  int tid = blockIdx.x * 256 + threadIdx.x;
  if (tid < 128 * 384) {
    int h = tid / 384, k = tid % 384;
    Wt1[tid] = f2bf(W1[k * 128 + h]);
  } else {
    int t2 = tid - 128 * 384;
    if (t2 < 128 * 128) {
      int o = t2 / 128, h = t2 % 128;
      Wt2[t2] = f2bf(W2[h * 128 + o]);
    }
  }
}

// One wave processes 32 edges end-to-end. Block = 4 waves = 128 edges.
// Stage1: H^T = W1^T(128x384) * concat^T(384x32)  via 16x16x32 bf16 MFMA
// Stage2: O^T = W2^T(128x128) * H^T(128x32)
// LayerNorm per edge (one edge's 128 outputs live on lanes e,e+16,e+32,e+48).
__global__ __launch_bounds__(256, 3) void edge_kernel(
    const float* __restrict__ node, const float* __restrict__ edge,
    const int* __restrict__ send, const int* __restrict__ recv,
    const unsigned short* __restrict__ Wt1,
    const unsigned short* __restrict__ Wt2,
    const float* __restrict__ b1, const float* __restrict__ b2,
    const float* __restrict__ gamma, const float* __restrict__ beta,
    float* __restrict__ out) {
  __shared__ unsigned short hbuf[4][32][136];  // [wave][edge_local][feat], pad 128->136

  const int lane = threadIdx.x & 63;
  const int wave = threadIdx.x >> 6;
  const int col = lane & 15;       // N index within 16-tile (edge)
  const int quad = lane >> 4;      // 0..3
  const int q4 = quad * 4;
  const int eBase = blockIdx.x * 128 + wave * 32;
  const bool active = eBase < NEDGES;

  if (active) {
    const int e0 = eBase + col;
    const int e1 = eBase + 16 + col;
    const float* src0[3] = { node + (size_t)send[e0] * D,
                             node + (size_t)recv[e0] * D,
                             edge + (size_t)e0 * D };
    const float* src1[3] = { node + (size_t)send[e1] * D,
                             node + (size_t)recv[e1] * D,
                             edge + (size_t)e1 * D };
    f32x4 acc[2][8];
#pragma unroll
    for (int m = 0; m < 8; ++m) {
      f32x4 bv = *(const f32x4*)(b1 + m * 16 + q4);
      acc[0][m] = bv; acc[1][m] = bv;
    }
#pragma unroll
    for (int kk = 0; kk < 12; ++kk) {
      const int seg = kk >> 2;                    // 0:sender 1:receiver 2:edge
      const int ks = (kk & 3) * 32 + quad * 8;    // within-segment k (0..127)
      const int kfull = kk * 32 + quad * 8;       // k into Wt1 row (0..383)
      short8 bf0 = cvt8(src0[seg] + ks);
      short8 bf1 = cvt8(src1[seg] + ks);
#pragma unroll
      for (int m = 0; m < 8; ++m) {
        short8 af = *(const short8*)(Wt1 + (size_t)(m * 16 + col) * 384 + kfull);
        acc[0][m] = __builtin_amdgcn_mfma_f32_16x16x32_bf16(af, bf0, acc[0][m], 0, 0, 0);
        acc[1][m] = __builtin_amdgcn_mfma_f32_16x16x32_bf16(af, bf1, acc[1][m], 0, 0, 0);
      }
    }
    // ReLU + pack to LDS as bf16, h layout [edge_local][feat]
#pragma unroll
    for (int g = 0; g < 2; ++g) {
#pragma unroll
      for (int m = 0; m < 8; ++m) {
        f32x4 v = acc[g][m];
        us4 w;
        w.x = f2bf(v[0] > 0.f ? v[0] : 0.f);
        w.y = f2bf(v[1] > 0.f ? v[1] : 0.f);
        w.z = f2bf(v[2] > 0.f ? v[2] : 0.f);
        w.w = f2bf(v[3] > 0.f ? v[3] : 0.f);
        *(us4*)&hbuf[wave][g * 16 + col][m * 16 + q4] = w;
      }
    }
  }

  __syncthreads();

  if (active) {
    f32x4 acc2[2][8];
#pragma unroll
    for (int m = 0; m < 8; ++m) {
      f32x4 bv = *(const f32x4*)(b2 + m * 16 + q4);
      acc2[0][m] = bv; acc2[1][m] = bv;
    }
#pragma unroll
    for (int kk = 0; kk < 4; ++kk) {
      const int kb = kk * 32 + quad * 8;
      short8 bf0 = *(const short8*)&hbuf[wave][col][kb];
      short8 bf1 = *(const short8*)&hbuf[wave][16 + col][kb];
#pragma unroll
      for (int m = 0; m < 8; ++m) {
        short8 af = *(const short8*)(Wt2 + (size_t)(m * 16 + col) * 128 + kb);
        acc2[0][m] = __builtin_amdgcn_mfma_f32_16x16x32_bf16(af, bf0, acc2[0][m], 0, 0, 0);
        acc2[1][m] = __builtin_amdgcn_mfma_f32_16x16x32_bf16(af, bf1, acc2[1][m], 0, 0, 0);
      }
    }
    // LayerNorm per edge + store
#pragma unroll
    for (int g = 0; g < 2; ++g) {
      float s = 0.f, ss = 0.f;
#pragma unroll
      for (int m = 0; m < 8; ++m) {
#pragma unroll
        for (int r = 0; r < 4; ++r) {
          float v = acc2[g][m][r];
          s += v; ss += v * v;
        }
      }
      s += __shfl_xor(s, 16);  s += __shfl_xor(s, 32);
      ss += __shfl_xor(ss, 16); ss += __shfl_xor(ss, 32);
      const float mean = s * (1.f / 128.f);
      const float var = ss * (1.f / 128.f) - mean * mean;
      const float rstd = rsqrtf(var + 1e-5f);
      const int e = eBase + g * 16 + col;
      float* op = out + (size_t)e * D;
#pragma unroll
      for (int m = 0; m < 8; ++m) {
        f32x4 gv = *(const f32x4*)(gamma + m * 16 + q4);
        f32x4 bv = *(const f32x4*)(beta + m * 16 + q4);
        f32x4 o;
#pragma unroll
        for (int r = 0; r < 4; ++r)
          o[r] = (acc2[g][m][r] - mean) * rstd * gv[r] + bv[r];
        *(f32x4*)(op + m * 16 + q4) = o;
      }
    }
  }
}

extern "C" void kernel_launch(void* const* d_in, const int* in_sizes, int n_in,
                              void* d_out, int out_size, void* d_ws, size_t ws_size,
                              hipStream_t stream) {
  const float* node  = (const float*)d_in[0];
  const float* edge  = (const float*)d_in[1];
  const int*   send  = (const int*)d_in[2];
  const int*   recv  = (const int*)d_in[3];
  const float* W1    = (const float*)d_in[4];
  const float* b1    = (const float*)d_in[5];
  const float* W2    = (const float*)d_in[6];
  const float* b2    = (const float*)d_in[7];
  const float* gam   = (const float*)d_in[8];
  const float* bet   = (const float*)d_in[9];
  float* out = (float*)d_out;

  unsigned short* Wt1 = (unsigned short*)d_ws;          // 128*384 bf16
  unsigned short* Wt2 = Wt1 + 128 * 384;                // 128*128 bf16

  prep_weights<<<256, 256, 0, stream>>>(W1, W2, Wt1, Wt2);

  const int nblocks = (NEDGES + 127) / 128;  // 3907
  edge_kernel<<<nblocks, 256, 0, stream>>>(node, edge, send, recv, Wt1, Wt2,
                                           b1, b2, gam, bet, out);
}

// Round 2
// 745.315 us; speedup vs baseline: 1.0129x; 1.0129x over previous
//
#include <hip/hip_runtime.h>

#define D 128
#define NEDGES 500000
#define NNODES 100000

typedef short short8 __attribute__((ext_vector_type(8)));
typedef float f32x4 __attribute__((ext_vector_type(4)));
typedef unsigned short us4 __attribute__((ext_vector_type(4)));

static __device__ __forceinline__ unsigned short f2bf(float f) {
  unsigned u = __builtin_bit_cast(unsigned, f);
  u += 0x7fff + ((u >> 16) & 1);   // RNE
  return (unsigned short)(u >> 16);
}

static __device__ __forceinline__ short8 cvt8v(f32x4 a, f32x4 b) {
  short8 r;
  r[0] = (short)f2bf(a[0]); r[1] = (short)f2bf(a[1]);
  r[2] = (short)f2bf(a[2]); r[3] = (short)f2bf(a[3]);
  r[4] = (short)f2bf(b[0]); r[5] = (short)f2bf(b[1]);
  r[6] = (short)f2bf(b[2]); r[7] = (short)f2bf(b[3]);
  return r;
}

// Transpose + bf16-convert weights into workspace.
__global__ void prep_weights(const float* __restrict__ W1,
                             const float* __restrict__ W2,
                             unsigned short* __restrict__ Wt1,
                             unsigned short* __restrict__ Wt2) {
  int tid = blockIdx.x * 256 + threadIdx.x;
  if (tid < 128 * 384) {
    int h = tid / 384, k = tid % 384;
    Wt1[tid] = f2bf(W1[k * 128 + h]);
  } else {
    int t2 = tid - 128 * 384;
    if (t2 < 128 * 128) {
      int o = t2 / 128, h = t2 % 128;
      Wt2[t2] = f2bf(W2[h * 128 + o]);
    }
  }
}

// One wave processes 32 edges end-to-end. Block = 4 waves = 128 edges.
// launch_bounds(256,4): 4 blocks/CU (LDS-capped), VGPR<=128.
__global__ __launch_bounds__(256, 4) void edge_kernel(
    const float* __restrict__ node, const float* __restrict__ edge,
    const int* __restrict__ send, const int* __restrict__ recv,
    const unsigned short* __restrict__ Wt1,
    const unsigned short* __restrict__ Wt2,
    const float* __restrict__ b1, const float* __restrict__ b2,
    const float* __restrict__ gamma, const float* __restrict__ beta,
    float* __restrict__ out) {
  __shared__ unsigned short hbuf[4][32][136];  // [wave][edge_local][feat]

  const int lane = threadIdx.x & 63;
  const int wave = threadIdx.x >> 6;
  const int col = lane & 15;
  const int quad = lane >> 4;
  const int q4 = quad * 4;
  const int eBase = blockIdx.x * 128 + wave * 32;
  const bool active = eBase < NEDGES;

  if (active) {
    const int e0 = eBase + col;
    const int e1 = eBase + 16 + col;
    const float* g0s = node + (size_t)send[e0] * D;
    const float* g0r = node + (size_t)recv[e0] * D;
    const float* g0e = edge + (size_t)e0 * D;
    const float* g1s = node + (size_t)send[e1] * D;
    const float* g1r = node + (size_t)recv[e1] * D;
    const float* g1e = edge + (size_t)e1 * D;

    f32x4 acc[2][8];
#pragma unroll
    for (int m = 0; m < 8; ++m) {
      f32x4 bv = *(const f32x4*)(b1 + m * 16 + q4);
      acc[0][m] = bv; acc[1][m] = bv;
    }

    // distance-2 software pipeline over 12 K-steps (3 segs x 4 chunks)
    f32x4 pl[2][2][2];  // [slot][group][half]
#define SRC0(seg) ((seg) == 0 ? g0s : (seg) == 1 ? g0r : g0e)
#define SRC1(seg) ((seg) == 0 ? g1s : (seg) == 1 ? g1r : g1e)
#define ISSUE(kk, slot)                                         \
    {                                                           \
      const int seg_ = (kk) >> 2;                               \
      const int ks_ = ((kk) & 3) * 32 + quad * 8;               \
      pl[slot][0][0] = *(const f32x4*)(SRC0(seg_) + ks_);       \
      pl[slot][0][1] = *(const f32x4*)(SRC0(seg_) + ks_ + 4);   \
      pl[slot][1][0] = *(const f32x4*)(SRC1(seg_) + ks_);       \
      pl[slot][1][1] = *(const f32x4*)(SRC1(seg_) + ks_ + 4);   \
    }

    ISSUE(0, 0)
    ISSUE(1, 1)
#pragma unroll
    for (int kk = 0; kk < 12; ++kk) {
      const int slot = kk & 1;
      short8 bf0 = cvt8v(pl[slot][0][0], pl[slot][0][1]);
      short8 bf1 = cvt8v(pl[slot][1][0], pl[slot][1][1]);
      if (kk + 2 < 12) ISSUE(kk + 2, slot)
      const int kfull = kk * 32 + quad * 8;
#pragma unroll
      for (int m = 0; m < 8; ++m) {
        short8 af = *(const short8*)(Wt1 + (size_t)(m * 16 + col) * 384 + kfull);
        acc[0][m] = __builtin_amdgcn_mfma_f32_16x16x32_bf16(af, bf0, acc[0][m], 0, 0, 0);
        acc[1][m] = __builtin_amdgcn_mfma_f32_16x16x32_bf16(af, bf1, acc[1][m], 0, 0, 0);
      }
    }
#undef ISSUE
#undef SRC0
#undef SRC1

    // ReLU + pack to LDS as bf16, layout [edge_local][feat]
#pragma unroll
    for (int g = 0; g < 2; ++g) {
#pragma unroll
      for (int m = 0; m < 8; ++m) {
        f32x4 v = acc[g][m];
        us4 w;
        w.x = f2bf(v[0] > 0.f ? v[0] : 0.f);
        w.y = f2bf(v[1] > 0.f ? v[1] : 0.f);
        w.z = f2bf(v[2] > 0.f ? v[2] : 0.f);
        w.w = f2bf(v[3] > 0.f ? v[3] : 0.f);
        *(us4*)&hbuf[wave][g * 16 + col][m * 16 + q4] = w;
      }
    }
  }

  __syncthreads();

  if (active) {
    f32x4 acc2[2][8];
#pragma unroll
    for (int m = 0; m < 8; ++m) {
      f32x4 bv = *(const f32x4*)(b2 + m * 16 + q4);
      acc2[0][m] = bv; acc2[1][m] = bv;
    }
#pragma unroll
    for (int kk = 0; kk < 4; ++kk) {
      const int kb = kk * 32 + quad * 8;
      short8 bf0 = *(const short8*)&hbuf[wave][col][kb];
      short8 bf1 = *(const short8*)&hbuf[wave][16 + col][kb];
#pragma unroll
      for (int m = 0; m < 8; ++m) {
        short8 af = *(const short8*)(Wt2 + (size_t)(m * 16 + col) * 128 + kb);
        acc2[0][m] = __builtin_amdgcn_mfma_f32_16x16x32_bf16(af, bf0, acc2[0][m], 0, 0, 0);
        acc2[1][m] = __builtin_amdgcn_mfma_f32_16x16x32_bf16(af, bf1, acc2[1][m], 0, 0, 0);
      }
    }
    // LayerNorm per edge + store
#pragma unroll
    for (int g = 0; g < 2; ++g) {
      float s = 0.f, ss = 0.f;
#pragma unroll
      for (int m = 0; m < 8; ++m) {
#pragma unroll
        for (int r = 0; r < 4; ++r) {
          float v = acc2[g][m][r];
          s += v; ss += v * v;
        }
      }
      s += __shfl_xor(s, 16);  s += __shfl_xor(s, 32);
      ss += __shfl_xor(ss, 16); ss += __shfl_xor(ss, 32);
      const float mean = s * (1.f / 128.f);
      const float var = ss * (1.f / 128.f) - mean * mean;
      const float rstd = rsqrtf(var + 1e-5f);
      const int e = eBase + g * 16 + col;
      float* op = out + (size_t)e * D;
#pragma unroll
      for (int m = 0; m < 8; ++m) {
        f32x4 gv = *(const f32x4*)(gamma + m * 16 + q4);
        f32x4 bv = *(const f32x4*)(beta + m * 16 + q4);
        f32x4 o;
#pragma unroll
        for (int r = 0; r < 4; ++r)
          o[r] = (acc2[g][m][r] - mean) * rstd * gv[r] + bv[r];
        *(f32x4*)(op + m * 16 + q4) = o;
      }
    }
  }
}

extern "C" void kernel_launch(void* const* d_in, const int* in_sizes, int n_in,
                              void* d_out, int out_size, void* d_ws, size_t ws_size,
                              hipStream_t stream) {
  const float* node  = (const float*)d_in[0];
  const float* edge  = (const float*)d_in[1];
  const int*   send  = (const int*)d_in[2];
  const int*   recv  = (const int*)d_in[3];
  const float* W1    = (const float*)d_in[4];
  const float* b1    = (const float*)d_in[5];
  const float* W2    = (const float*)d_in[6];
  const float* b2    = (const float*)d_in[7];
  const float* gam   = (const float*)d_in[8];
  const float* bet   = (const float*)d_in[9];
  float* out = (float*)d_out;

  unsigned short* Wt1 = (unsigned short*)d_ws;          // 128*384 bf16
  unsigned short* Wt2 = Wt1 + 128 * 384;                // 128*128 bf16

  prep_weights<<<256, 256, 0, stream>>>(W1, W2, Wt1, Wt2);

  const int nblocks = (NEDGES + 127) / 128;  // 3907
  edge_kernel<<<nblocks, 256, 0, stream>>>(node, edge, send, recv, Wt1, Wt2,
                                           b1, b2, gam, bet, out);
}